// Round 7
// baseline (249.322 us; speedup 1.0000x reference)
//
#include <hip/hip_runtime.h>
#include <stdint.h>

// Problem constants
#define B_    2
#define NQ_   1024
#define NKV_  4096
#define DQ_   1024
#define H_    16
#define DH_   64
#define INNER_ 1024

typedef unsigned short u16;
typedef uint32_t u32;
typedef __bf16 bf16x8 __attribute__((ext_vector_type(8)));
typedef float  f32x4  __attribute__((ext_vector_type(4)));

__device__ __forceinline__ u16 f2bf(float x) {           // RNE
  union { float f; uint32_t u; } v; v.f = x;
  uint32_t r = v.u + 0x7FFFu + ((v.u >> 16) & 1u);
  return (u16)(r >> 16);
}
__device__ __forceinline__ u32 pack2(float a, float b) { // RNE pair
  return (u32)f2bf(a) | ((u32)f2bf(b) << 16);
}
__device__ __forceinline__ u32 pack2rn(float a, float b) { // fast RN via v_perm (3 VALU)
  union { float f; u32 u; } x, y; x.f = a; y.f = b;
  return __builtin_amdgcn_perm(y.u + 0x8000u, x.u + 0x8000u, 0x07060302u);
}
__device__ __forceinline__ float bf2f(u16 s) {
  union { float f; uint32_t u; } v; v.u = ((uint32_t)s) << 16; return v.f;
}

// async global->LDS, 16B/lane; lds base wave-uniform, hw adds lane*16
__device__ __forceinline__ void gload16(const void* g, void* l) {
  __builtin_amdgcn_global_load_lds((const __attribute__((address_space(1))) void*)g,
                                   (__attribute__((address_space(3))) void*)l,
                                   16, 0, 0);
}

// ---------------- prep: weight transpose+cast only, W[K][N] f32 -> Wt[N][K] bf16 --------
// units [0,1024): Wq; [1024,3072): Wkv; [3072,4096): Wout.
__global__ __launch_bounds__(256) void prep(const float* __restrict__ Wq,
                                            const float* __restrict__ Wkv,
                                            const float* __restrict__ Wout,
                                            u16* __restrict__ WqT,
                                            u16* __restrict__ WkvT,
                                            u16* __restrict__ WoutT) {
  __shared__ float tile[32][33];
  int u = blockIdx.x;
  const float* W; u16* Wt; int K, N, local, nsh;
  if (u < 1024)      { W = Wq;   Wt = WqT;   K = 1024; N = 1024; local = u;        nsh = 5; }
  else if (u < 3072) { W = Wkv;  Wt = WkvT;  K = 1024; N = 2048; local = u - 1024; nsh = 6; }
  else               { W = Wout; Wt = WoutT; K = 1024; N = 1024; local = u - 3072; nsh = 5; }
  int n0 = (local & ((1 << nsh) - 1)) * 32;
  int k0 = (local >> nsh) * 32;
  int tx = threadIdx.x & 31, ty = threadIdx.x >> 5;   // 32 x 8
  for (int i = ty; i < 32; i += 8)
    tile[i][tx] = W[(size_t)(k0 + i) * N + n0 + tx];
  __syncthreads();
  for (int i = ty; i < 32; i += 8)
    Wt[(size_t)(n0 + i) * K + k0 + tx] = f2bf(tile[tx][i]);
}

// ---------------- merged Q/K/V projection GEMM, A read directly as fp32 -----------------
// A staged fp32 via gload16 into XOR-swizzled 16B groups; converted to bf16 in-register
// at fragment load (pack2rn). B from pre-transposed bf16 weights (m97 path).
// units [0,128): q = x Wq -> qb; [128,1152): kv = ctx Wkv -> kb / vT scatter.
__global__ __launch_bounds__(256) void qkv_gemm(const float* __restrict__ x,
                                                const float* __restrict__ ctx,
                                                const u16* __restrict__ WqT,
                                                const u16* __restrict__ WkvT,
                                                u16* __restrict__ qb,
                                                u16* __restrict__ kb,
                                                u16* __restrict__ vTb) {
  __shared__ __align__(16) float Afs[128 * 32];   // 16 KB, 8 groups/row, g^=(row&7)
  __shared__ __align__(16) u16  Bs[128 * 32];     // 8 KB
  const int tid = threadIdx.x;
  const int lane = tid & 63;
  const int w = tid >> 6;
  const int wr = w >> 1, wc = w & 1;
  const int l15 = lane & 15, quad = lane >> 4;

  int bid = blockIdx.x;
  const float* A; const u16* Bt; int m0, n0, mode;
  if (bid < 128) { m0 = (bid >> 3) * 128; n0 = (bid & 7) * 128; A = x;   Bt = WqT;  mode = 0; }
  else { bid -= 128; m0 = (bid >> 4) * 128; n0 = (bid & 15) * 128; A = ctx; Bt = WkvT;
         mode = (n0 < 1024) ? 1 : 2; }
  const int K = 1024;

  const float* Ab = A + (size_t)m0 * K;
  const u16* Bb = Bt + (size_t)n0 * K;

  f32x4 acc[4][4] = {};

  // B chunk ids (16B chunks of the 8KB bf16 tile), 2 per thread
  const int q1 = w * 64 + lane, q2 = q1 + 256;
  const int br1 = q1 >> 2, bc1 = (q1 & 3) << 3;
  const int br2 = q2 >> 2, bc2 = (q2 & 3) << 3;
  // A chunk ids (16B = 4 fp32; 1024 chunks), 4 per thread; slot s holds global group
  // g = (s ^ (s>>3)) & 7 of row s>>3  (XOR swizzle, DMA-compatible)
  int arow[4], ag[4];
#pragma unroll
  for (int j = 0; j < 4; ++j) {
    int s = j * 256 + tid;
    arow[j] = s >> 3;
    ag[j] = (s ^ arow[j]) & 7;
  }

  for (int k0 = 0; k0 < K; k0 += 32) {
    __syncthreads();
#pragma unroll
    for (int j = 0; j < 4; ++j)
      gload16(Ab + (size_t)arow[j] * K + k0 + ag[j] * 4, &Afs[(j * 256 + w * 64) * 4]);
    gload16(Bb + (size_t)br1 * K + k0 + bc1, &Bs[w * 512]);
    gload16(Bb + (size_t)br2 * K + k0 + bc2, &Bs[2048 + w * 512]);
    __syncthreads();
    bf16x8 af[4], bfr[4];
#pragma unroll
    for (int i = 0; i < 4; ++i) {        // fp32 frag -> bf16x8 (2-way LDS conflicts: free)
      int r = wr * 64 + i * 16 + l15;
      int g0 = (2 * quad) ^ (r & 7), g1 = (2 * quad + 1) ^ (r & 7);
      f32x4 a0 = *(const f32x4*)&Afs[r * 32 + g0 * 4];
      f32x4 a1 = *(const f32x4*)&Afs[r * 32 + g1 * 4];
      union { u32 u[4]; bf16x8 v; } cv;
      cv.u[0] = pack2rn(a0[0], a0[1]); cv.u[1] = pack2rn(a0[2], a0[3]);
      cv.u[2] = pack2rn(a1[0], a1[1]); cv.u[3] = pack2rn(a1[2], a1[3]);
      af[i] = cv.v;
    }
#pragma unroll
    for (int j = 0; j < 4; ++j)
      bfr[j] = *(const bf16x8*)&Bs[(wc * 64 + j * 16 + l15) * 32 + quad * 8];
#pragma unroll
    for (int i = 0; i < 4; ++i)
#pragma unroll
      for (int j = 0; j < 4; ++j)
        acc[i][j] = __builtin_amdgcn_mfma_f32_16x16x32_bf16(af[i], bfr[j], acc[i][j], 0, 0, 0);
  }

  if (mode == 2) {
    // V: scatter into vT[(b*16+h)*64+dh][kv]; 4 consecutive kv rows/lane -> 8B store
    const int bb = m0 >> 12;
#pragma unroll
    for (int i = 0; i < 4; ++i) {
      int kvr = (m0 & 4095) + wr * 64 + i * 16 + quad * 4;
#pragma unroll
      for (int j = 0; j < 4; ++j) {
        int c = (n0 - 1024) + wc * 64 + j * 16 + l15;
        int h = c >> 6, dh = c & 63;
        uint2 st;
        st.x = pack2(acc[i][j][0], acc[i][j][1]);
        st.y = pack2(acc[i][j][2], acc[i][j][3]);
        *(uint2*)&vTb[((size_t)((bb * 16 + h) * 64 + dh)) * NKV_ + kvr] = st;
      }
    }
    return;
  }

  u16* out = (mode == 0) ? qb : kb;
  const int N = 1024;
#pragma unroll
  for (int i = 0; i < 4; ++i)
#pragma unroll
    for (int j = 0; j < 4; ++j) {
      int col = n0 + wc * 64 + j * 16 + l15;
#pragma unroll
      for (int r = 0; r < 4; ++r) {
        int row = m0 + wr * 64 + i * 16 + quad * 4 + r;
        out[(size_t)row * N + col] = f2bf(acc[i][j][r]);
      }
    }
}

// ---------------- out-proj GEMM: 64x128 tiles -> 256 blocks (full GPU) ------------------
__global__ __launch_bounds__(256) void out_gemm(const u16* __restrict__ A,
                                                const u16* __restrict__ Bt,
                                                float* __restrict__ Cout,
                                                const float* __restrict__ bias) {
  __shared__ __align__(16) u16 As[64 * 32];    // 4 KB
  __shared__ __align__(16) u16 Bs[128 * 32];   // 8 KB
  const int tid = threadIdx.x;
  const int lane = tid & 63;
  const int w = tid >> 6;
  const int wr = w >> 1, wc = w & 1;           // wave covers 32M x 64N
  const int l15 = lane & 15, quad = lane >> 4;
  const int unit = blockIdx.x;
  const int m0 = (unit >> 3) * 64, n0 = (unit & 7) * 128;
  const int K = 1024, N = 1024;

  const u16* Ab = A + (size_t)m0 * K;
  const u16* Bb = Bt + (size_t)n0 * K;
  f32x4 acc[2][4] = {};

  const int ar = tid >> 2, ac = (tid & 3) << 3;          // A: 256 chunks, 1/thread
  const int q1 = w * 64 + lane, q2 = q1 + 256;           // B: 512 chunks, 2/thread
  const int br1 = q1 >> 2, bc1 = (q1 & 3) << 3;
  const int br2 = q2 >> 2, bc2 = (q2 & 3) << 3;

  for (int k0 = 0; k0 < K; k0 += 32) {
    __syncthreads();
    gload16(Ab + (size_t)ar * K + k0 + ac, &As[w * 512]);
    gload16(Bb + (size_t)br1 * K + k0 + bc1, &Bs[w * 512]);
    gload16(Bb + (size_t)br2 * K + k0 + bc2, &Bs[2048 + w * 512]);
    __syncthreads();
    bf16x8 af[2], bfr[4];
#pragma unroll
    for (int i = 0; i < 2; ++i)
      af[i] = *(const bf16x8*)&As[(wr * 32 + i * 16 + l15) * 32 + quad * 8];
#pragma unroll
    for (int j = 0; j < 4; ++j)
      bfr[j] = *(const bf16x8*)&Bs[(wc * 64 + j * 16 + l15) * 32 + quad * 8];
#pragma unroll
    for (int i = 0; i < 2; ++i)
#pragma unroll
      for (int j = 0; j < 4; ++j)
        acc[i][j] = __builtin_amdgcn_mfma_f32_16x16x32_bf16(af[i], bfr[j], acc[i][j], 0, 0, 0);
  }

#pragma unroll
  for (int i = 0; i < 2; ++i)
#pragma unroll
    for (int j = 0; j < 4; ++j) {
      int col = n0 + wc * 64 + j * 16 + l15;
      float bv = bias[col];
#pragma unroll
      for (int r = 0; r < 4; ++r) {
        int row = m0 + wr * 32 + i * 16 + quad * 4 + r;
        Cout[(size_t)row * N + col] = acc[i][j][r] + bv;
      }
    }
}

// ---------------- flash attention (round-5 proven): kv-sliced waves ---------------------
// Block = 64 q-rows x one (b,h); 256 thr / 4 waves; 2 blocks/CU (53 KB LDS).
// Grid x=bh so the 16 q-blocks sharing one K/V head get the same blockid%8 -> same XCD L2.
__global__ __launch_bounds__(256, 2) void attn_kernel(const u16* __restrict__ qg,
                                                      const u16* __restrict__ kb,
                                                      const u16* __restrict__ vT,
                                                      u16* __restrict__ attn_out) {
  __shared__ __align__(16) u16 Ks[128 * 64];       // [kv][dh], 16B groups XOR-swizzled
  __shared__ __align__(16) u16 Vs[64 * 128];       // [dh][kv], XOR-swizzled (16 groups/row)
  __shared__ __align__(16) u32 P32[4 * 4 * 16 * 20]; // [w][t][q=l15][20]: wave-private pairs
  __shared__ float Lr[4][4][16];                   // [w][t][q] partial l

  const int tid = threadIdx.x;
  const int lane = tid & 63;
  const int w = tid >> 6;
  const int l15 = lane & 15, quad = lane >> 4;
  const int bh = blockIdx.x, b = bh >> 4, h = bh & 15;
  const int q0 = blockIdx.y * 64;

  const float SC = 0.125f * 1.44269504088896340736f;   // dh^-0.5 * log2(e)
  union { u16 s[8]; bf16x8 v; } qf[4][2];
#pragma unroll
  for (int t = 0; t < 4; ++t)
#pragma unroll
    for (int kc = 0; kc < 2; ++kc) {
      const u16* qp = qg + (size_t)(b * NQ_ + q0 + t * 16 + l15) * INNER_ + h * 64 +
                      kc * 32 + quad * 8;
      union { u16 s[8]; uint4 u; } tmp;
      tmp.u = *(const uint4*)qp;
#pragma unroll
      for (int e = 0; e < 8; ++e) qf[t][kc].s[e] = f2bf(bf2f(tmp.s[e]) * SC);
    }

  f32x4 Oacc[4][4] = {};
  float l_lane[4] = {0.f, 0.f, 0.f, 0.f};

  for (int it = 0; it < 32; ++it) {
    const int j0 = it * 128;
    __syncthreads();
#pragma unroll
    for (int i = 0; i < 4; ++i) {
      int s = i * 256 + tid;
      int kr = s >> 3, kg = (s ^ kr) & 7;
      gload16(kb + (size_t)(b * NKV_ + j0 + kr) * 1024 + h * 64 + kg * 8,
              &Ks[(i * 256 + w * 64) * 8]);
      int vr = s >> 4, vg = (s ^ vr) & 15;
      gload16(vT + (size_t)(bh * 64 + vr) * NKV_ + j0 + vg * 8,
              &Vs[(i * 256 + w * 64) * 8]);
    }
    __syncthreads();

    bf16x8 kf[2][2];
#pragma unroll
    for (int kvt = 0; kvt < 2; ++kvt)
#pragma unroll
      for (int kc = 0; kc < 2; ++kc)
        kf[kvt][kc] = *(const bf16x8*)
          &Ks[(w * 32 + kvt * 16 + l15) * 64 + (((kc * 4 + quad) ^ l15) & 7) * 8];
    f32x4 sacc[2][4] = {};
#pragma unroll
    for (int kvt = 0; kvt < 2; ++kvt)
#pragma unroll
      for (int t = 0; t < 4; ++t)
#pragma unroll
        for (int kc = 0; kc < 2; ++kc)
          sacc[kvt][t] = __builtin_amdgcn_mfma_f32_16x16x32_bf16(
              kf[kvt][kc], qf[t][kc].v, sacc[kvt][t], 0, 0, 0);

#pragma unroll
    for (int kvt = 0; kvt < 2; ++kvt)
#pragma unroll
      for (int t = 0; t < 4; ++t) {
        float p0 = __builtin_amdgcn_exp2f(sacc[kvt][t][0]);
        float p1 = __builtin_amdgcn_exp2f(sacc[kvt][t][1]);
        float p2 = __builtin_amdgcn_exp2f(sacc[kvt][t][2]);
        float p3 = __builtin_amdgcn_exp2f(sacc[kvt][t][3]);
        l_lane[t] += (p0 + p1) + (p2 + p3);
        uint2 pk; pk.x = pack2rn(p0, p1); pk.y = pack2rn(p2, p3);
        *(uint2*)&P32[((w * 4 + t) * 16 + l15) * 20 + kvt * 8 + quad * 2] = pk;
      }

    bf16x8 vf[4], pf[4];
#pragma unroll
    for (int d = 0; d < 4; ++d)
      vf[d] = *(const bf16x8*)
        &Vs[(d * 16 + l15) * 128 + (((w * 4 + quad) ^ l15) & 15) * 8];
#pragma unroll
    for (int t = 0; t < 4; ++t)
      pf[t] = *(const bf16x8*)&P32[((w * 4 + t) * 16 + l15) * 20 + quad * 4];
#pragma unroll
    for (int d = 0; d < 4; ++d)
#pragma unroll
      for (int t = 0; t < 4; ++t)
        Oacc[d][t] = __builtin_amdgcn_mfma_f32_16x16x32_bf16(vf[d], pf[t], Oacc[d][t],
                                                             0, 0, 0);
  }

#pragma unroll
  for (int t = 0; t < 4; ++t) {
    l_lane[t] += __shfl_xor(l_lane[t], 16);
    l_lane[t] += __shfl_xor(l_lane[t], 32);
  }
  if (quad == 0) {
#pragma unroll
    for (int t = 0; t < 4; ++t) Lr[w][t][l15] = l_lane[t];
  }
  __syncthreads();
  float inv = 1.0f / (Lr[0][w][l15] + Lr[1][w][l15] + Lr[2][w][l15] + Lr[3][w][l15]);

  float* red = (float*)P32;
  u16* ob = attn_out + (size_t)(b * NQ_ + q0 + w * 16 + l15) * INNER_ + h * 64;
#pragma unroll
  for (int d = 0; d < 4; ++d) {
    __syncthreads();
#pragma unroll
    for (int t = 0; t < 4; ++t)
      *(f32x4*)&red[(w * 4 + t) * 256 + quad * 64 + l15 * 4] = Oacc[d][t];
    __syncthreads();
    f32x4 r = *(const f32x4*)&red[(0 * 4 + w) * 256 + quad * 64 + l15 * 4];
#pragma unroll
    for (int ww = 1; ww < 4; ++ww) {
      f32x4 c = *(const f32x4*)&red[(ww * 4 + w) * 256 + quad * 64 + l15 * 4];
      r[0] += c[0]; r[1] += c[1]; r[2] += c[2]; r[3] += c[3];
    }
    *(u32*)(ob + d * 16 + quad * 4)     = pack2(r[0] * inv, r[1] * inv);
    *(u32*)(ob + d * 16 + quad * 4 + 2) = pack2(r[2] * inv, r[3] * inv);
  }
}

// ---------------- driver ----------------
extern "C" void kernel_launch(void* const* d_in, const int* in_sizes, int n_in,
                              void* d_out, int out_size, void* d_ws, size_t ws_size,
                              hipStream_t stream) {
  const float* x    = (const float*)d_in[0];
  const float* ctx  = (const float*)d_in[1];
  const float* Wq   = (const float*)d_in[2];
  const float* Wkv  = (const float*)d_in[3];
  const float* Wout = (const float*)d_in[4];
  const float* bout = (const float*)d_in[5];

  char* ws = (char*)d_ws;
  u16* ab    = (u16*)(ws + (size_t)( 0u << 20));  // 4 MB
  u16* WqT   = (u16*)(ws + (size_t)(20u << 20));  // 2 MB
  u16* WkvT  = (u16*)(ws + (size_t)(22u << 20));  // 4 MB
  u16* WoutT = (u16*)(ws + (size_t)(26u << 20));  // 2 MB
  u16* qb    = (u16*)(ws + (size_t)(28u << 20));  // 4 MB
  u16* kb    = (u16*)(ws + (size_t)(32u << 20));  // 16 MB
  u16* vTb   = (u16*)(ws + (size_t)(48u << 20));  // 16 MB

  // weight transposes only (x/ctx cast folded into qkv_gemm staging)
  prep<<<4096, 256, 0, stream>>>(Wq, Wkv, Wout, WqT, WkvT, WoutT);
  // q/k/v projections, A read directly as fp32 (1152 blocks)
  qkv_gemm<<<1152, 256, 0, stream>>>(x, ctx, WqT, WkvT, qb, kb, vTb);
  // fused softmax attention: 512 blocks x 256 threads, x=bh for XCD L2 locality
  attn_kernel<<<dim3(32, 16), 256, 0, stream>>>(qb, kb, vTb, ab);
  // out = attn Wout + b_out : fp32, 256 blocks
  out_gemm<<<256, 256, 0, stream>>>(ab, WoutT, (float*)d_out, bout);
}

// Round 8
// 240.522 us; speedup vs baseline: 1.0366x; 1.0366x over previous
//
#include <hip/hip_runtime.h>
#include <stdint.h>

// Problem constants
#define B_    2
#define NQ_   1024
#define NKV_  4096
#define DQ_   1024
#define H_    16
#define DH_   64
#define INNER_ 1024

typedef unsigned short u16;
typedef uint32_t u32;
typedef __bf16 bf16x8 __attribute__((ext_vector_type(8)));
typedef float  f32x4  __attribute__((ext_vector_type(4)));

__device__ __forceinline__ u16 f2bf(float x) {           // RNE
  union { float f; uint32_t u; } v; v.f = x;
  uint32_t r = v.u + 0x7FFFu + ((v.u >> 16) & 1u);
  return (u16)(r >> 16);
}
__device__ __forceinline__ u32 pack2(float a, float b) { // RNE pair
  return (u32)f2bf(a) | ((u32)f2bf(b) << 16);
}
__device__ __forceinline__ u32 pack2rn(float a, float b) { // fast RN via v_perm (3 VALU)
  union { float f; u32 u; } x, y; x.f = a; y.f = b;
  return __builtin_amdgcn_perm(y.u + 0x8000u, x.u + 0x8000u, 0x07060302u);
}
__device__ __forceinline__ float bf2f(u16 s) {
  union { float f; uint32_t u; } v; v.u = ((uint32_t)s) << 16; return v.f;
}

// async global->LDS, 16B/lane; lds base wave-uniform, hw adds lane*16
__device__ __forceinline__ void gload16(const void* g, void* l) {
  __builtin_amdgcn_global_load_lds((const __attribute__((address_space(1))) void*)g,
                                   (__attribute__((address_space(3))) void*)l,
                                   16, 0, 0);
}

// ---------------- fused prep: casts + weight transposes + counter init ------------------
// blocks [0,2048): cast x; [2048,10240): cast ctx; [10240,11264): Wq^T;
// [11264,13312): Wkv^T; [13312,14336): Wout^T.  Block 0 also zeroes the qkv steal counter.
__global__ __launch_bounds__(256) void prep(const float* __restrict__ x,
                                            const float* __restrict__ ctx,
                                            const float* __restrict__ Wq,
                                            const float* __restrict__ Wkv,
                                            const float* __restrict__ Wout,
                                            u16* __restrict__ xb,
                                            u16* __restrict__ ctxb,
                                            u16* __restrict__ WqT,
                                            u16* __restrict__ WkvT,
                                            u16* __restrict__ WoutT,
                                            u32* __restrict__ cnt) {
  int bid = blockIdx.x;
  if (bid == 0 && threadIdx.x == 0) *cnt = 0u;   // steal base for qkv (next dispatch)
  if (bid < 10240) {                       // elementwise cast, 4 elems/thread
    const float* src; u16* dst; int blk;
    if (bid < 2048) { src = x; dst = xb; blk = bid; }
    else            { src = ctx; dst = ctxb; blk = bid - 2048; }
    int i = (blk * 256 + threadIdx.x) * 4;
    float4 v = *(const float4*)(src + i);
    uint2 o; o.x = pack2(v.x, v.y); o.y = pack2(v.z, v.w);
    *(uint2*)(dst + i) = o;
    return;
  }
  // transpose+cast W[K][N] -> Wt[N][K]
  __shared__ float tile[32][33];
  const float* W; u16* Wt; int K, N, local, nsh;
  if (bid < 11264)      { W = Wq;   Wt = WqT;   K = 1024; N = 1024; local = bid - 10240; nsh = 5; }
  else if (bid < 13312) { W = Wkv;  Wt = WkvT;  K = 1024; N = 2048; local = bid - 11264; nsh = 6; }
  else                  { W = Wout; Wt = WoutT; K = 1024; N = 1024; local = bid - 13312; nsh = 5; }
  int n0 = (local & ((1 << nsh) - 1)) * 32;
  int k0 = (local >> nsh) * 32;
  int tx = threadIdx.x & 31, ty = threadIdx.x >> 5;   // 32 x 8
  for (int i = ty; i < 32; i += 8)
    tile[i][tx] = W[(size_t)(k0 + i) * N + n0 + tx];
  __syncthreads();
  for (int i = ty; i < 32; i += 8)
    Wt[(size_t)(n0 + i) * K + k0 + tx] = f2bf(tile[tx][i]);
}

// ---------------- one qkv GEMM tile (m97 structure, bf16 staged, K=1024) ----------------
// units [0,128): q = x Wq -> qb; [128,1152): kv = ctx Wkv -> kb / vT scatter
__device__ __forceinline__ void qkv_tile(int unit, int tid, u16* As, u16* Bs,
                                         const u16* __restrict__ xb,
                                         const u16* __restrict__ ctxb,
                                         const u16* __restrict__ WqT,
                                         const u16* __restrict__ WkvT,
                                         u16* __restrict__ qb, u16* __restrict__ kb,
                                         u16* __restrict__ vTb) {
  const int lane = tid & 63;
  const int w = tid >> 6;
  const int wr = w >> 1, wc = w & 1;
  const int l15 = lane & 15, quad = lane >> 4;

  int bid = unit;
  const u16 *A, *Bt; int m0, n0, mode;
  if (bid < 128) { m0 = (bid >> 3) * 128; n0 = (bid & 7) * 128; A = xb;   Bt = WqT;  mode = 0; }
  else { bid -= 128; m0 = (bid >> 4) * 128; n0 = (bid & 15) * 128; A = ctxb; Bt = WkvT;
         mode = (n0 < 1024) ? 1 : 2; }
  const int K = 1024;

  const u16* Ab = A + (size_t)m0 * K;
  const u16* Bb = Bt + (size_t)n0 * K;

  f32x4 acc[4][4] = {};

  const int q1 = w * 64 + lane;          // 16B-chunk ids of the 8KB tile
  const int q2 = q1 + 256;
  const int ar1 = q1 >> 2, ac1 = (q1 & 3) << 3;
  const int ar2 = q2 >> 2, ac2 = (q2 & 3) << 3;

  for (int k0 = 0; k0 < K; k0 += 32) {
    __syncthreads();
    gload16(Ab + (size_t)ar1 * K + k0 + ac1, &As[w * 512]);
    gload16(Ab + (size_t)ar2 * K + k0 + ac2, &As[2048 + w * 512]);
    gload16(Bb + (size_t)ar1 * K + k0 + ac1, &Bs[w * 512]);
    gload16(Bb + (size_t)ar2 * K + k0 + ac2, &Bs[2048 + w * 512]);
    __syncthreads();
    bf16x8 af[4], bfr[4];
#pragma unroll
    for (int i = 0; i < 4; ++i)
      af[i] = *(const bf16x8*)&As[(wr * 64 + i * 16 + l15) * 32 + quad * 8];
#pragma unroll
    for (int j = 0; j < 4; ++j)
      bfr[j] = *(const bf16x8*)&Bs[(wc * 64 + j * 16 + l15) * 32 + quad * 8];
#pragma unroll
    for (int i = 0; i < 4; ++i)
#pragma unroll
      for (int j = 0; j < 4; ++j)
        acc[i][j] = __builtin_amdgcn_mfma_f32_16x16x32_bf16(af[i], bfr[j], acc[i][j], 0, 0, 0);
  }

  if (mode == 2) {
    // V: scatter into vT[(b*16+h)*64+dh][kv]; 4 consecutive kv rows/lane -> 8B store
    const int bb = m0 >> 12;
#pragma unroll
    for (int i = 0; i < 4; ++i) {
      int kvr = (m0 & 4095) + wr * 64 + i * 16 + quad * 4;
#pragma unroll
      for (int j = 0; j < 4; ++j) {
        int c = (n0 - 1024) + wc * 64 + j * 16 + l15;
        int h = c >> 6, dh = c & 63;
        uint2 st;
        st.x = pack2(acc[i][j][0], acc[i][j][1]);
        st.y = pack2(acc[i][j][2], acc[i][j][3]);
        *(uint2*)&vTb[((size_t)((bb * 16 + h) * 64 + dh)) * NKV_ + kvr] = st;
      }
    }
    return;
  }

  u16* out = (mode == 0) ? qb : kb;
  const int N = 1024;
#pragma unroll
  for (int i = 0; i < 4; ++i)
#pragma unroll
    for (int j = 0; j < 4; ++j) {
      int col = n0 + wc * 64 + j * 16 + l15;
#pragma unroll
      for (int r = 0; r < 4; ++r) {
        int row = m0 + wr * 64 + i * 16 + quad * 4 + r;
        out[(size_t)row * N + col] = f2bf(acc[i][j][r]);
      }
    }
}

// ---------------- persistent qkv GEMM: 512 blocks, atomic work-stealing over 1152 -------
__global__ __launch_bounds__(256) void qkv_gemm(const u16* __restrict__ xb,
                                                const u16* __restrict__ ctxb,
                                                const u16* __restrict__ WqT,
                                                const u16* __restrict__ WkvT,
                                                u16* __restrict__ qb,
                                                u16* __restrict__ kb,
                                                u16* __restrict__ vTb,
                                                u32* __restrict__ cnt) {
  __shared__ __align__(16) u16 As[128 * 32];
  __shared__ __align__(16) u16 Bs[128 * 32];
  __shared__ int sh_next;
  const int tid = threadIdx.x;
  int unit = blockIdx.x;
  while (unit < 1152) {
    qkv_tile(unit, tid, As, Bs, xb, ctxb, WqT, WkvT, qb, kb, vTb);
    if (tid == 0) sh_next = 512 + (int)atomicAdd(cnt, 1u);
    __syncthreads();
    unit = sh_next;
  }
}

// ---------------- out-proj GEMM: 64x128 tiles -> 256 blocks (full GPU) ------------------
__global__ __launch_bounds__(256) void out_gemm(const u16* __restrict__ A,
                                                const u16* __restrict__ Bt,
                                                float* __restrict__ Cout,
                                                const float* __restrict__ bias) {
  __shared__ __align__(16) u16 As[64 * 32];    // 4 KB
  __shared__ __align__(16) u16 Bs[128 * 32];   // 8 KB
  const int tid = threadIdx.x;
  const int lane = tid & 63;
  const int w = tid >> 6;
  const int wr = w >> 1, wc = w & 1;           // wave covers 32M x 64N
  const int l15 = lane & 15, quad = lane >> 4;
  const int unit = blockIdx.x;
  const int m0 = (unit >> 3) * 64, n0 = (unit & 7) * 128;
  const int K = 1024, N = 1024;

  const u16* Ab = A + (size_t)m0 * K;
  const u16* Bb = Bt + (size_t)n0 * K;
  f32x4 acc[2][4] = {};

  const int ar = tid >> 2, ac = (tid & 3) << 3;          // A: 256 chunks, 1/thread
  const int q1 = w * 64 + lane, q2 = q1 + 256;           // B: 512 chunks, 2/thread
  const int br1 = q1 >> 2, bc1 = (q1 & 3) << 3;
  const int br2 = q2 >> 2, bc2 = (q2 & 3) << 3;

  for (int k0 = 0; k0 < K; k0 += 32) {
    __syncthreads();
    gload16(Ab + (size_t)ar * K + k0 + ac, &As[w * 512]);
    gload16(Bb + (size_t)br1 * K + k0 + bc1, &Bs[w * 512]);
    gload16(Bb + (size_t)br2 * K + k0 + bc2, &Bs[2048 + w * 512]);
    __syncthreads();
    bf16x8 af[2], bfr[4];
#pragma unroll
    for (int i = 0; i < 2; ++i)
      af[i] = *(const bf16x8*)&As[(wr * 32 + i * 16 + l15) * 32 + quad * 8];
#pragma unroll
    for (int j = 0; j < 4; ++j)
      bfr[j] = *(const bf16x8*)&Bs[(wc * 64 + j * 16 + l15) * 32 + quad * 8];
#pragma unroll
    for (int i = 0; i < 2; ++i)
#pragma unroll
      for (int j = 0; j < 4; ++j)
        acc[i][j] = __builtin_amdgcn_mfma_f32_16x16x32_bf16(af[i], bfr[j], acc[i][j], 0, 0, 0);
  }

#pragma unroll
  for (int i = 0; i < 2; ++i)
#pragma unroll
    for (int j = 0; j < 4; ++j) {
      int col = n0 + wc * 64 + j * 16 + l15;
      float bv = bias[col];
#pragma unroll
      for (int r = 0; r < 4; ++r) {
        int row = m0 + wr * 32 + i * 16 + quad * 4 + r;
        Cout[(size_t)row * N + col] = acc[i][j][r] + bv;
      }
    }
}

// ---------------- flash attention (round-5 proven): kv-sliced waves ---------------------
// Block = 64 q-rows x one (b,h); 256 thr / 4 waves; 2 blocks/CU (53 KB LDS).
// Grid x=bh so the 16 q-blocks sharing one K/V head get the same blockid%8 -> same XCD L2.
__global__ __launch_bounds__(256, 2) void attn_kernel(const u16* __restrict__ qg,
                                                      const u16* __restrict__ kb,
                                                      const u16* __restrict__ vT,
                                                      u16* __restrict__ attn_out) {
  __shared__ __align__(16) u16 Ks[128 * 64];       // [kv][dh], 16B groups XOR-swizzled
  __shared__ __align__(16) u16 Vs[64 * 128];       // [dh][kv], XOR-swizzled (16 groups/row)
  __shared__ __align__(16) u32 P32[4 * 4 * 16 * 20]; // [w][t][q=l15][20]: wave-private pairs
  __shared__ float Lr[4][4][16];                   // [w][t][q] partial l

  const int tid = threadIdx.x;
  const int lane = tid & 63;
  const int w = tid >> 6;
  const int l15 = lane & 15, quad = lane >> 4;
  const int bh = blockIdx.x, b = bh >> 4, h = bh & 15;
  const int q0 = blockIdx.y * 64;

  const float SC = 0.125f * 1.44269504088896340736f;   // dh^-0.5 * log2(e)
  union { u16 s[8]; bf16x8 v; } qf[4][2];
#pragma unroll
  for (int t = 0; t < 4; ++t)
#pragma unroll
    for (int kc = 0; kc < 2; ++kc) {
      const u16* qp = qg + (size_t)(b * NQ_ + q0 + t * 16 + l15) * INNER_ + h * 64 +
                      kc * 32 + quad * 8;
      union { u16 s[8]; uint4 u; } tmp;
      tmp.u = *(const uint4*)qp;
#pragma unroll
      for (int e = 0; e < 8; ++e) qf[t][kc].s[e] = f2bf(bf2f(tmp.s[e]) * SC);
    }

  f32x4 Oacc[4][4] = {};
  float l_lane[4] = {0.f, 0.f, 0.f, 0.f};

  for (int it = 0; it < 32; ++it) {
    const int j0 = it * 128;
    __syncthreads();
#pragma unroll
    for (int i = 0; i < 4; ++i) {
      int s = i * 256 + tid;
      int kr = s >> 3, kg = (s ^ kr) & 7;
      gload16(kb + (size_t)(b * NKV_ + j0 + kr) * 1024 + h * 64 + kg * 8,
              &Ks[(i * 256 + w * 64) * 8]);
      int vr = s >> 4, vg = (s ^ vr) & 15;
      gload16(vT + (size_t)(bh * 64 + vr) * NKV_ + j0 + vg * 8,
              &Vs[(i * 256 + w * 64) * 8]);
    }
    __syncthreads();

    bf16x8 kf[2][2];
#pragma unroll
    for (int kvt = 0; kvt < 2; ++kvt)
#pragma unroll
      for (int kc = 0; kc < 2; ++kc)
        kf[kvt][kc] = *(const bf16x8*)
          &Ks[(w * 32 + kvt * 16 + l15) * 64 + (((kc * 4 + quad) ^ l15) & 7) * 8];
    f32x4 sacc[2][4] = {};
#pragma unroll
    for (int kvt = 0; kvt < 2; ++kvt)
#pragma unroll
      for (int t = 0; t < 4; ++t)
#pragma unroll
        for (int kc = 0; kc < 2; ++kc)
          sacc[kvt][t] = __builtin_amdgcn_mfma_f32_16x16x32_bf16(
              kf[kvt][kc], qf[t][kc].v, sacc[kvt][t], 0, 0, 0);

#pragma unroll
    for (int kvt = 0; kvt < 2; ++kvt)
#pragma unroll
      for (int t = 0; t < 4; ++t) {
        float p0 = __builtin_amdgcn_exp2f(sacc[kvt][t][0]);
        float p1 = __builtin_amdgcn_exp2f(sacc[kvt][t][1]);
        float p2 = __builtin_amdgcn_exp2f(sacc[kvt][t][2]);
        float p3 = __builtin_amdgcn_exp2f(sacc[kvt][t][3]);
        l_lane[t] += (p0 + p1) + (p2 + p3);
        uint2 pk; pk.x = pack2rn(p0, p1); pk.y = pack2rn(p2, p3);
        *(uint2*)&P32[((w * 4 + t) * 16 + l15) * 20 + kvt * 8 + quad * 2] = pk;
      }

    bf16x8 vf[4], pf[4];
#pragma unroll
    for (int d = 0; d < 4; ++d)
      vf[d] = *(const bf16x8*)
        &Vs[(d * 16 + l15) * 128 + (((w * 4 + quad) ^ l15) & 15) * 8];
#pragma unroll
    for (int t = 0; t < 4; ++t)
      pf[t] = *(const bf16x8*)&P32[((w * 4 + t) * 16 + l15) * 20 + quad * 4];
#pragma unroll
    for (int d = 0; d < 4; ++d)
#pragma unroll
      for (int t = 0; t < 4; ++t)
        Oacc[d][t] = __builtin_amdgcn_mfma_f32_16x16x32_bf16(vf[d], pf[t], Oacc[d][t],
                                                             0, 0, 0);
  }

#pragma unroll
  for (int t = 0; t < 4; ++t) {
    l_lane[t] += __shfl_xor(l_lane[t], 16);
    l_lane[t] += __shfl_xor(l_lane[t], 32);
  }
  if (quad == 0) {
#pragma unroll
    for (int t = 0; t < 4; ++t) Lr[w][t][l15] = l_lane[t];
  }
  __syncthreads();
  float inv = 1.0f / (Lr[0][w][l15] + Lr[1][w][l15] + Lr[2][w][l15] + Lr[3][w][l15]);

  float* red = (float*)P32;
  u16* ob = attn_out + (size_t)(b * NQ_ + q0 + w * 16 + l15) * INNER_ + h * 64;
#pragma unroll
  for (int d = 0; d < 4; ++d) {
    __syncthreads();
#pragma unroll
    for (int t = 0; t < 4; ++t)
      *(f32x4*)&red[(w * 4 + t) * 256 + quad * 64 + l15 * 4] = Oacc[d][t];
    __syncthreads();
    f32x4 r = *(const f32x4*)&red[(0 * 4 + w) * 256 + quad * 64 + l15 * 4];
#pragma unroll
    for (int ww = 1; ww < 4; ++ww) {
      f32x4 c = *(const f32x4*)&red[(ww * 4 + w) * 256 + quad * 64 + l15 * 4];
      r[0] += c[0]; r[1] += c[1]; r[2] += c[2]; r[3] += c[3];
    }
    *(u32*)(ob + d * 16 + quad * 4)     = pack2(r[0] * inv, r[1] * inv);
    *(u32*)(ob + d * 16 + quad * 4 + 2) = pack2(r[2] * inv, r[3] * inv);
  }
}

// ---------------- driver ----------------
extern "C" void kernel_launch(void* const* d_in, const int* in_sizes, int n_in,
                              void* d_out, int out_size, void* d_ws, size_t ws_size,
                              hipStream_t stream) {
  const float* x    = (const float*)d_in[0];
  const float* ctx  = (const float*)d_in[1];
  const float* Wq   = (const float*)d_in[2];
  const float* Wkv  = (const float*)d_in[3];
  const float* Wout = (const float*)d_in[4];
  const float* bout = (const float*)d_in[5];

  char* ws = (char*)d_ws;
  u16* xb    = (u16*)(ws + (size_t)( 0u << 20));  // 4 MB  [dead after qkv_gemm]
  u16* ab    = (u16*)(ws + (size_t)( 0u << 20));  // 4 MB  [reuses xb]
  u16* ctxb  = (u16*)(ws + (size_t)( 4u << 20));  // 16 MB [dead after qkv_gemm]
  u16* WqT   = (u16*)(ws + (size_t)(20u << 20));  // 2 MB
  u16* WkvT  = (u16*)(ws + (size_t)(22u << 20));  // 4 MB
  u16* WoutT = (u16*)(ws + (size_t)(26u << 20));  // 2 MB
  u16* qb    = (u16*)(ws + (size_t)(28u << 20));  // 4 MB
  u16* kb    = (u16*)(ws + (size_t)(32u << 20));  // 16 MB
  u16* vTb   = (u16*)(ws + (size_t)(48u << 20));  // 16 MB
  u32* cnt   = (u32*)d_out;    // steal counter: dead region until out_gemm overwrites

  // casts + weight transposes (+ counter init) in one dispatch
  prep<<<14336, 256, 0, stream>>>(x, ctx, Wq, Wkv, Wout, xb, ctxb, WqT, WkvT, WoutT, cnt);
  // q/k/v projections: 512 persistent blocks, work-stealing over 1152 tiles
  qkv_gemm<<<512, 256, 0, stream>>>(xb, ctxb, WqT, WkvT, qb, kb, vTb, cnt);
  // fused softmax attention: 512 blocks x 256 threads, x=bh for XCD L2 locality
  attn_kernel<<<dim3(32, 16), 256, 0, stream>>>(qb, kb, vTb, ab);
  // out = attn Wout + b_out : fp32, 256 blocks
  out_gemm<<<256, 256, 0, stream>>>(ab, WoutT, (float*)d_out, bout);
}

// Round 9
// 224.733 us; speedup vs baseline: 1.1094x; 1.0703x over previous
//
#include <hip/hip_runtime.h>
#include <stdint.h>

// Problem constants
#define B_    2
#define NQ_   1024
#define NKV_  4096
#define DQ_   1024
#define H_    16
#define DH_   64
#define INNER_ 1024

typedef unsigned short u16;
typedef uint32_t u32;
typedef __bf16 bf16x8 __attribute__((ext_vector_type(8)));
typedef float  f32x4  __attribute__((ext_vector_type(4)));

__device__ __forceinline__ u16 f2bf(float x) {           // RNE
  union { float f; uint32_t u; } v; v.f = x;
  uint32_t r = v.u + 0x7FFFu + ((v.u >> 16) & 1u);
  return (u16)(r >> 16);
}
__device__ __forceinline__ u32 pack2(float a, float b) { // RNE pair
  return (u32)f2bf(a) | ((u32)f2bf(b) << 16);
}
__device__ __forceinline__ u32 pack2rn(float a, float b) { // fast RN via v_perm (3 VALU)
  union { float f; u32 u; } x, y; x.f = a; y.f = b;
  return __builtin_amdgcn_perm(y.u + 0x8000u, x.u + 0x8000u, 0x07060302u);
}
__device__ __forceinline__ float bf2f(u16 s) {
  union { float f; uint32_t u; } v; v.u = ((uint32_t)s) << 16; return v.f;
}

// async global->LDS, 16B/lane; lds base wave-uniform, hw adds lane*16
__device__ __forceinline__ void gload16(const void* g, void* l) {
  __builtin_amdgcn_global_load_lds((const __attribute__((address_space(1))) void*)g,
                                   (__attribute__((address_space(3))) void*)l,
                                   16, 0, 0);
}

// ---------------- fused prep: casts + weight transposes in ONE dispatch -----------------
// blocks [0,2048): cast x; [2048,10240): cast ctx; [10240,11264): Wq^T;
// [11264,13312): Wkv^T; [13312,14336): Wout^T.
__global__ __launch_bounds__(256) void prep(const float* __restrict__ x,
                                            const float* __restrict__ ctx,
                                            const float* __restrict__ Wq,
                                            const float* __restrict__ Wkv,
                                            const float* __restrict__ Wout,
                                            u16* __restrict__ xb,
                                            u16* __restrict__ ctxb,
                                            u16* __restrict__ WqT,
                                            u16* __restrict__ WkvT,
                                            u16* __restrict__ WoutT) {
  int bid = blockIdx.x;
  if (bid < 10240) {                       // elementwise cast, 4 elems/thread
    const float* src; u16* dst; int blk;
    if (bid < 2048) { src = x; dst = xb; blk = bid; }
    else            { src = ctx; dst = ctxb; blk = bid - 2048; }
    int i = (blk * 256 + threadIdx.x) * 4;
    float4 v = *(const float4*)(src + i);
    uint2 o; o.x = pack2(v.x, v.y); o.y = pack2(v.z, v.w);
    *(uint2*)(dst + i) = o;
    return;
  }
  // transpose+cast W[K][N] -> Wt[N][K]
  __shared__ float tile[32][33];
  const float* W; u16* Wt; int K, N, local, nsh;
  if (bid < 11264)      { W = Wq;   Wt = WqT;   K = 1024; N = 1024; local = bid - 10240; nsh = 5; }
  else if (bid < 13312) { W = Wkv;  Wt = WkvT;  K = 1024; N = 2048; local = bid - 11264; nsh = 6; }
  else                  { W = Wout; Wt = WoutT; K = 1024; N = 1024; local = bid - 13312; nsh = 5; }
  int n0 = (local & ((1 << nsh) - 1)) * 32;
  int k0 = (local >> nsh) * 32;
  int tx = threadIdx.x & 31, ty = threadIdx.x >> 5;   // 32 x 8
  for (int i = ty; i < 32; i += 8)
    tile[i][tx] = W[(size_t)(k0 + i) * N + n0 + tx];
  __syncthreads();
  for (int i = ty; i < 32; i += 8)
    Wt[(size_t)(n0 + i) * K + k0 + tx] = f2bf(tile[tx][i]);
}

// ---------------- merged Q/K/V projection GEMM (round-5 proven: static 1152 blocks) -----
// blocks [0,128): q = x Wq -> qb; [128,1152): kv = ctx Wkv -> kb / vT scatter.
// Static grid: ~4 blocks/CU resident (VGPR 80) -> cross-block overlap hides barrier
// drain; HW scheduler absorbs the 128-tile tail. (R8 measured: persistent 512-block
// work-stealing pins 2 blocks/CU and REGRESSES 62->81 us. Do not re-try.)
__global__ __launch_bounds__(256) void qkv_gemm(const u16* __restrict__ xb,
                                                const u16* __restrict__ ctxb,
                                                const u16* __restrict__ WqT,
                                                const u16* __restrict__ WkvT,
                                                u16* __restrict__ qb,
                                                u16* __restrict__ kb,
                                                u16* __restrict__ vTb) {
  __shared__ __align__(16) u16 As[128 * 32];
  __shared__ __align__(16) u16 Bs[128 * 32];
  const int tid = threadIdx.x;
  const int lane = tid & 63;
  const int w = tid >> 6;
  const int wr = w >> 1, wc = w & 1;
  const int l15 = lane & 15, quad = lane >> 4;

  int bid = blockIdx.x;
  const u16 *A, *Bt; int m0, n0, mode;
  if (bid < 128) { m0 = (bid >> 3) * 128; n0 = (bid & 7) * 128; A = xb;   Bt = WqT;  mode = 0; }
  else { bid -= 128; m0 = (bid >> 4) * 128; n0 = (bid & 15) * 128; A = ctxb; Bt = WkvT;
         mode = (n0 < 1024) ? 1 : 2; }
  const int K = 1024;

  const u16* Ab = A + (size_t)m0 * K;
  const u16* Bb = Bt + (size_t)n0 * K;

  f32x4 acc[4][4] = {};

  const int q1 = w * 64 + lane;          // 16B-chunk ids of the 8KB tile
  const int q2 = q1 + 256;
  const int ar1 = q1 >> 2, ac1 = (q1 & 3) << 3;
  const int ar2 = q2 >> 2, ac2 = (q2 & 3) << 3;

  for (int k0 = 0; k0 < K; k0 += 32) {
    __syncthreads();
    gload16(Ab + (size_t)ar1 * K + k0 + ac1, &As[w * 512]);
    gload16(Ab + (size_t)ar2 * K + k0 + ac2, &As[2048 + w * 512]);
    gload16(Bb + (size_t)ar1 * K + k0 + ac1, &Bs[w * 512]);
    gload16(Bb + (size_t)ar2 * K + k0 + ac2, &Bs[2048 + w * 512]);
    __syncthreads();
    bf16x8 af[4], bfr[4];
#pragma unroll
    for (int i = 0; i < 4; ++i)
      af[i] = *(const bf16x8*)&As[(wr * 64 + i * 16 + l15) * 32 + quad * 8];
#pragma unroll
    for (int j = 0; j < 4; ++j)
      bfr[j] = *(const bf16x8*)&Bs[(wc * 64 + j * 16 + l15) * 32 + quad * 8];
#pragma unroll
    for (int i = 0; i < 4; ++i)
#pragma unroll
      for (int j = 0; j < 4; ++j)
        acc[i][j] = __builtin_amdgcn_mfma_f32_16x16x32_bf16(af[i], bfr[j], acc[i][j], 0, 0, 0);
  }

  if (mode == 2) {
    // V: scatter into vT[(b*16+h)*64+dh][kv]; 4 consecutive kv rows/lane -> 8B store
    const int bb = m0 >> 12;
#pragma unroll
    for (int i = 0; i < 4; ++i) {
      int kvr = (m0 & 4095) + wr * 64 + i * 16 + quad * 4;
#pragma unroll
      for (int j = 0; j < 4; ++j) {
        int c = (n0 - 1024) + wc * 64 + j * 16 + l15;
        int h = c >> 6, dh = c & 63;
        uint2 st;
        st.x = pack2(acc[i][j][0], acc[i][j][1]);
        st.y = pack2(acc[i][j][2], acc[i][j][3]);
        *(uint2*)&vTb[((size_t)((bb * 16 + h) * 64 + dh)) * NKV_ + kvr] = st;
      }
    }
    return;
  }

  u16* out = (mode == 0) ? qb : kb;
  const int N = 1024;
#pragma unroll
  for (int i = 0; i < 4; ++i)
#pragma unroll
    for (int j = 0; j < 4; ++j) {
      int col = n0 + wc * 64 + j * 16 + l15;
#pragma unroll
      for (int r = 0; r < 4; ++r) {
        int row = m0 + wr * 64 + i * 16 + quad * 4 + r;
        out[(size_t)row * N + col] = f2bf(acc[i][j][r]);
      }
    }
}

// ---------------- out-proj GEMM: 64x128 tiles -> 256 blocks (full GPU) ------------------
__global__ __launch_bounds__(256) void out_gemm(const u16* __restrict__ A,
                                                const u16* __restrict__ Bt,
                                                float* __restrict__ Cout,
                                                const float* __restrict__ bias) {
  __shared__ __align__(16) u16 As[64 * 32];    // 4 KB
  __shared__ __align__(16) u16 Bs[128 * 32];   // 8 KB
  const int tid = threadIdx.x;
  const int lane = tid & 63;
  const int w = tid >> 6;
  const int wr = w >> 1, wc = w & 1;           // wave covers 32M x 64N
  const int l15 = lane & 15, quad = lane >> 4;
  const int unit = blockIdx.x;
  const int m0 = (unit >> 3) * 64, n0 = (unit & 7) * 128;
  const int K = 1024, N = 1024;

  const u16* Ab = A + (size_t)m0 * K;
  const u16* Bb = Bt + (size_t)n0 * K;
  f32x4 acc[2][4] = {};

  const int ar = tid >> 2, ac = (tid & 3) << 3;          // A: 256 chunks, 1/thread
  const int q1 = w * 64 + lane, q2 = q1 + 256;           // B: 512 chunks, 2/thread
  const int br1 = q1 >> 2, bc1 = (q1 & 3) << 3;
  const int br2 = q2 >> 2, bc2 = (q2 & 3) << 3;

  for (int k0 = 0; k0 < K; k0 += 32) {
    __syncthreads();
    gload16(Ab + (size_t)ar * K + k0 + ac, &As[w * 512]);
    gload16(Bb + (size_t)br1 * K + k0 + bc1, &Bs[w * 512]);
    gload16(Bb + (size_t)br2 * K + k0 + bc2, &Bs[2048 + w * 512]);
    __syncthreads();
    bf16x8 af[2], bfr[4];
#pragma unroll
    for (int i = 0; i < 2; ++i)
      af[i] = *(const bf16x8*)&As[(wr * 32 + i * 16 + l15) * 32 + quad * 8];
#pragma unroll
    for (int j = 0; j < 4; ++j)
      bfr[j] = *(const bf16x8*)&Bs[(wc * 64 + j * 16 + l15) * 32 + quad * 8];
#pragma unroll
    for (int i = 0; i < 2; ++i)
#pragma unroll
      for (int j = 0; j < 4; ++j)
        acc[i][j] = __builtin_amdgcn_mfma_f32_16x16x32_bf16(af[i], bfr[j], acc[i][j], 0, 0, 0);
  }

#pragma unroll
  for (int i = 0; i < 2; ++i)
#pragma unroll
    for (int j = 0; j < 4; ++j) {
      int col = n0 + wc * 64 + j * 16 + l15;
      float bv = bias[col];
#pragma unroll
      for (int r = 0; r < 4; ++r) {
        int row = m0 + wr * 32 + i * 16 + quad * 4 + r;
        Cout[(size_t)row * N + col] = acc[i][j][r] + bv;
      }
    }
}

// ---------------- flash attention (round-5 proven): kv-sliced waves ---------------------
// Block = 64 q-rows x one (b,h); 256 thr / 4 waves; 2 blocks/CU (53 KB LDS).
// Grid x=bh so the 16 q-blocks sharing one K/V head get the same blockid%8 -> same XCD L2.
__global__ __launch_bounds__(256, 2) void attn_kernel(const u16* __restrict__ qg,
                                                      const u16* __restrict__ kb,
                                                      const u16* __restrict__ vT,
                                                      u16* __restrict__ attn_out) {
  __shared__ __align__(16) u16 Ks[128 * 64];       // [kv][dh], 16B groups XOR-swizzled
  __shared__ __align__(16) u16 Vs[64 * 128];       // [dh][kv], XOR-swizzled (16 groups/row)
  __shared__ __align__(16) u32 P32[4 * 4 * 16 * 20]; // [w][t][q=l15][20]: wave-private pairs
  __shared__ float Lr[4][4][16];                   // [w][t][q] partial l

  const int tid = threadIdx.x;
  const int lane = tid & 63;
  const int w = tid >> 6;
  const int l15 = lane & 15, quad = lane >> 4;
  const int bh = blockIdx.x, b = bh >> 4, h = bh & 15;
  const int q0 = blockIdx.y * 64;

  const float SC = 0.125f * 1.44269504088896340736f;   // dh^-0.5 * log2(e)
  union { u16 s[8]; bf16x8 v; } qf[4][2];
#pragma unroll
  for (int t = 0; t < 4; ++t)
#pragma unroll
    for (int kc = 0; kc < 2; ++kc) {
      const u16* qp = qg + (size_t)(b * NQ_ + q0 + t * 16 + l15) * INNER_ + h * 64 +
                      kc * 32 + quad * 8;
      union { u16 s[8]; uint4 u; } tmp;
      tmp.u = *(const uint4*)qp;
#pragma unroll
      for (int e = 0; e < 8; ++e) qf[t][kc].s[e] = f2bf(bf2f(tmp.s[e]) * SC);
    }

  f32x4 Oacc[4][4] = {};
  float l_lane[4] = {0.f, 0.f, 0.f, 0.f};

  for (int it = 0; it < 32; ++it) {
    const int j0 = it * 128;
    __syncthreads();
#pragma unroll
    for (int i = 0; i < 4; ++i) {
      int s = i * 256 + tid;
      int kr = s >> 3, kg = (s ^ kr) & 7;
      gload16(kb + (size_t)(b * NKV_ + j0 + kr) * 1024 + h * 64 + kg * 8,
              &Ks[(i * 256 + w * 64) * 8]);
      int vr = s >> 4, vg = (s ^ vr) & 15;
      gload16(vT + (size_t)(bh * 64 + vr) * NKV_ + j0 + vg * 8,
              &Vs[(i * 256 + w * 64) * 8]);
    }
    __syncthreads();

    bf16x8 kf[2][2];
#pragma unroll
    for (int kvt = 0; kvt < 2; ++kvt)
#pragma unroll
      for (int kc = 0; kc < 2; ++kc)
        kf[kvt][kc] = *(const bf16x8*)
          &Ks[(w * 32 + kvt * 16 + l15) * 64 + (((kc * 4 + quad) ^ l15) & 7) * 8];
    f32x4 sacc[2][4] = {};
#pragma unroll
    for (int kvt = 0; kvt < 2; ++kvt)
#pragma unroll
      for (int t = 0; t < 4; ++t)
#pragma unroll
        for (int kc = 0; kc < 2; ++kc)
          sacc[kvt][t] = __builtin_amdgcn_mfma_f32_16x16x32_bf16(
              kf[kvt][kc], qf[t][kc].v, sacc[kvt][t], 0, 0, 0);

#pragma unroll
    for (int kvt = 0; kvt < 2; ++kvt)
#pragma unroll
      for (int t = 0; t < 4; ++t) {
        float p0 = __builtin_amdgcn_exp2f(sacc[kvt][t][0]);
        float p1 = __builtin_amdgcn_exp2f(sacc[kvt][t][1]);
        float p2 = __builtin_amdgcn_exp2f(sacc[kvt][t][2]);
        float p3 = __builtin_amdgcn_exp2f(sacc[kvt][t][3]);
        l_lane[t] += (p0 + p1) + (p2 + p3);
        uint2 pk; pk.x = pack2rn(p0, p1); pk.y = pack2rn(p2, p3);
        *(uint2*)&P32[((w * 4 + t) * 16 + l15) * 20 + kvt * 8 + quad * 2] = pk;
      }

    bf16x8 vf[4], pf[4];
#pragma unroll
    for (int d = 0; d < 4; ++d)
      vf[d] = *(const bf16x8*)
        &Vs[(d * 16 + l15) * 128 + (((w * 4 + quad) ^ l15) & 15) * 8];
#pragma unroll
    for (int t = 0; t < 4; ++t)
      pf[t] = *(const bf16x8*)&P32[((w * 4 + t) * 16 + l15) * 20 + quad * 4];
#pragma unroll
    for (int d = 0; d < 4; ++d)
#pragma unroll
      for (int t = 0; t < 4; ++t)
        Oacc[d][t] = __builtin_amdgcn_mfma_f32_16x16x32_bf16(vf[d], pf[t], Oacc[d][t],
                                                             0, 0, 0);
  }

#pragma unroll
  for (int t = 0; t < 4; ++t) {
    l_lane[t] += __shfl_xor(l_lane[t], 16);
    l_lane[t] += __shfl_xor(l_lane[t], 32);
  }
  if (quad == 0) {
#pragma unroll
    for (int t = 0; t < 4; ++t) Lr[w][t][l15] = l_lane[t];
  }
  __syncthreads();
  float inv = 1.0f / (Lr[0][w][l15] + Lr[1][w][l15] + Lr[2][w][l15] + Lr[3][w][l15]);

  float* red = (float*)P32;
  u16* ob = attn_out + (size_t)(b * NQ_ + q0 + w * 16 + l15) * INNER_ + h * 64;
#pragma unroll
  for (int d = 0; d < 4; ++d) {
    __syncthreads();
#pragma unroll
    for (int t = 0; t < 4; ++t)
      *(f32x4*)&red[(w * 4 + t) * 256 + quad * 64 + l15 * 4] = Oacc[d][t];
    __syncthreads();
    f32x4 r = *(const f32x4*)&red[(0 * 4 + w) * 256 + quad * 64 + l15 * 4];
#pragma unroll
    for (int ww = 1; ww < 4; ++ww) {
      f32x4 c = *(const f32x4*)&red[(ww * 4 + w) * 256 + quad * 64 + l15 * 4];
      r[0] += c[0]; r[1] += c[1]; r[2] += c[2]; r[3] += c[3];
    }
    *(u32*)(ob + d * 16 + quad * 4)     = pack2(r[0] * inv, r[1] * inv);
    *(u32*)(ob + d * 16 + quad * 4 + 2) = pack2(r[2] * inv, r[3] * inv);
  }
}

// ---------------- driver ----------------
extern "C" void kernel_launch(void* const* d_in, const int* in_sizes, int n_in,
                              void* d_out, int out_size, void* d_ws, size_t ws_size,
                              hipStream_t stream) {
  const float* x    = (const float*)d_in[0];
  const float* ctx  = (const float*)d_in[1];
  const float* Wq   = (const float*)d_in[2];
  const float* Wkv  = (const float*)d_in[3];
  const float* Wout = (const float*)d_in[4];
  const float* bout = (const float*)d_in[5];

  char* ws = (char*)d_ws;
  u16* xb    = (u16*)(ws + (size_t)( 0u << 20));  // 4 MB  [dead after qkv_gemm]
  u16* ab    = (u16*)(ws + (size_t)( 0u << 20));  // 4 MB  [reuses xb]
  u16* ctxb  = (u16*)(ws + (size_t)( 4u << 20));  // 16 MB [dead after qkv_gemm]
  u16* WqT   = (u16*)(ws + (size_t)(20u << 20));  // 2 MB
  u16* WkvT  = (u16*)(ws + (size_t)(22u << 20));  // 4 MB
  u16* WoutT = (u16*)(ws + (size_t)(26u << 20));  // 2 MB
  u16* qb    = (u16*)(ws + (size_t)(28u << 20));  // 4 MB
  u16* kb    = (u16*)(ws + (size_t)(32u << 20));  // 16 MB
  u16* vTb   = (u16*)(ws + (size_t)(48u << 20));  // 16 MB

  // casts + weight transposes in one dispatch
  prep<<<14336, 256, 0, stream>>>(x, ctx, Wq, Wkv, Wout, xb, ctxb, WqT, WkvT, WoutT);
  // q/k/v projections: static 1152 blocks (round-5 proven)
  qkv_gemm<<<1152, 256, 0, stream>>>(xb, ctxb, WqT, WkvT, qb, kb, vTb);
  // fused softmax attention: 512 blocks x 256 threads, x=bh for XCD L2 locality
  attn_kernel<<<dim3(32, 16), 256, 0, stream>>>(qb, kb, vTb, ab);
  // out = attn Wout + b_out : fp32, 256 blocks
  out_gemm<<<256, 256, 0, stream>>>(ab, WoutT, (float*)d_out, bout);
}